// Round 5
// baseline (500.570 us; speedup 1.0000x reference)
//
#include <hip/hip_runtime.h>
#include <hip/hip_bf16.h>

// B=4, S=2048, D=1024, H=8, HD=128, FF=4096
// bf16 MFMA (f32 acc); fp32 softmax/LayerNorm.
// R1: XOR-swizzled LDS -> bank conflicts killed.
// R3: attn on 32x32x16 MFMA, Q in regs, single-pass softmax (max=0).
// R4: GEMM BK=64, split-K=2 on N=1024 GEMMs, LN-fused reduction.
// R5: attn K-loop restructured: S^T = K*Q^T so P^T B-frags are built in
//     registers (shfl_xor 32) -- P LDS round-trip deleted; Q's LDS buffer
//     becomes a 2nd KV buffer -> pipelined staging (issue gll16, then MFMA,
//     then barrier), 2 barriers/kt instead of 4 with zero overlap.

typedef float floatx4 __attribute__((ext_vector_type(4)));
typedef float floatx16 __attribute__((ext_vector_type(16)));
typedef short bf16x8 __attribute__((ext_vector_type(8)));

#define DEVI __device__ __forceinline__

typedef const __attribute__((address_space(1))) unsigned int* gas1_t;
typedef __attribute__((address_space(3))) unsigned int* las3_t;

DEVI void gll16(const void* g, void* l) {
  __builtin_amdgcn_global_load_lds((gas1_t)g, (las3_t)l, 16, 0, 0);
}

DEVI short bfbits(float f) {
  __hip_bfloat16 h = __float2bfloat16(f);
  return *reinterpret_cast<short*>(&h);
}

// ---------------------------------------------------------------------------
// C[M,N] = A[M,K](bf16 rm) * BT[N,K](bf16 rm). BK=64, 128x128 tile.
// EPI 0: C bf16 | 2: C bf16 = relu(acc) | 4: f32 partial (split-K)
// ---------------------------------------------------------------------------
template<int EPI, int SPLITK>
__global__ __launch_bounds__(256, 4) void gemm_bt(
    const __hip_bfloat16* __restrict__ A,
    const __hip_bfloat16* __restrict__ BT,
    float* __restrict__ Cf, float* __restrict__ Cf2,
    __hip_bfloat16* __restrict__ Cb,
    int M, int N, int K)
{
  __shared__ __hip_bfloat16 As[128 * 64];
  __shared__ __hip_bfloat16 Bs[128 * 64];
  const int tid = threadIdx.x;
  const int wave = tid >> 6, lane = tid & 63;
  const int lane15 = lane & 15, quad = lane >> 4;
  const int row0 = blockIdx.x * 128, col0 = blockIdx.y * 128;
  const int wr = (wave >> 1) * 64, wc = (wave & 1) * 64;
  const int Kh = K / SPLITK;
  const size_t kofs = (SPLITK > 1) ? (size_t)blockIdx.z * Kh : 0;

  floatx4 acc[4][4] = {};

  const int srow = tid >> 3;
  const int sblk = (tid & 7) ^ (srow & 7);
  const __hip_bfloat16* Ag = A + (size_t)(row0 + srow) * K + kofs + sblk * 8;
  const __hip_bfloat16* Bg = BT + (size_t)(col0 + srow) * K + kofs + sblk * 8;
  char* Asl = (char*)As + tid * 16;
  char* Bsl = (char*)Bs + tid * 16;
  const size_t rstep = (size_t)32 * K;

  const int x7 = lane15 & 7;
  for (int k0 = 0; k0 < Kh; k0 += 64) {
    __syncthreads();
#pragma unroll
    for (int p = 0; p < 4; p++) {
      gll16(Ag + k0 + p * rstep, Asl + p * 4096);
      gll16(Bg + k0 + p * rstep, Bsl + p * 4096);
    }
    __syncthreads();
#pragma unroll
    for (int kc = 0; kc < 2; kc++) {
      bf16x8 af[4], bb[4];
#pragma unroll
      for (int t = 0; t < 4; t++) {
        const int r = wr + t * 16 + lane15;
        af[t] = *(const bf16x8*)((const char*)As + r * 128 + (((kc * 4 + quad) ^ x7) << 4));
      }
#pragma unroll
      for (int t = 0; t < 4; t++) {
        const int r = wc + t * 16 + lane15;
        bb[t] = *(const bf16x8*)((const char*)Bs + r * 128 + (((kc * 4 + quad) ^ x7) << 4));
      }
#pragma unroll
      for (int i = 0; i < 4; i++)
#pragma unroll
        for (int j = 0; j < 4; j++)
          acc[i][j] = __builtin_amdgcn_mfma_f32_16x16x32_bf16(af[i], bb[j], acc[i][j], 0, 0, 0);
    }
  }

  float* Cp = (SPLITK > 1 && blockIdx.z) ? Cf2 : Cf;
#pragma unroll
  for (int i = 0; i < 4; i++) {
    const int mb = row0 + wr + i * 16 + quad * 4;
#pragma unroll
    for (int j = 0; j < 4; j++) {
      const int n = col0 + wc + j * 16 + lane15;
#pragma unroll
      for (int r = 0; r < 4; r++) {
        const size_t idx = (size_t)(mb + r) * N + n;
        const float v = acc[i][j][r];
        if (EPI == 0) {
          Cb[idx] = __float2bfloat16(v);
        } else if (EPI == 2) {
          Cb[idx] = __float2bfloat16(v > 0.f ? v : 0.f);
        } else {
          Cp[idx] = v;
        }
      }
    }
  }
}

// ---------------------------------------------------------------------------
// Flash attention, pipelined. Grid (16 q-tiles of 128, 32 b*h). 4 waves;
// wave owns 32 q (q = wave*32 + l31). S^T = K*Q^T so each lane holds the
// full P row for its q; P^T B-frags built via shfl_xor(32). Two LDS buffers
// (Ak for K, Bq for Q-then-V) -> staging issued before MFMA, 2 barriers/kt.
// ---------------------------------------------------------------------------
__global__ __launch_bounds__(256, 2) void attn_kernel(
    const __hip_bfloat16* __restrict__ qkv,
    const __hip_bfloat16* __restrict__ Vt,
    __hip_bfloat16* __restrict__ vals)
{
  __shared__ __hip_bfloat16 Ak[128 * 128];   // K tiles
  __shared__ __hip_bfloat16 Bq[128 * 128];   // Q, then V tiles

  const int tid = threadIdx.x;
  const int wave = tid >> 6, lane = tid & 63;
  const int l31 = lane & 31, l5 = lane >> 5;
  const int qt = blockIdx.x, bh = blockIdx.y;
  const int b = bh >> 3, h = bh & 7;
  const size_t tokbase = (size_t)b * 2048;
  const float scale = 0.08838834764831845f;  // 1/sqrt(128)

  const int sw8 = ((tid & 15) ^ (tid >> 4)) * 8;
  const int srow = tid >> 4;
  const __hip_bfloat16* qg  = qkv + (tokbase + qt * 128) * 3072 + h * 384 + sw8;
  const __hip_bfloat16* kg0 = qkv + tokbase * 3072 + h * 384 + 128 + sw8;
  const __hip_bfloat16* vg0 = Vt + (size_t)bh * 128 * 2048 + sw8;

  // stage Q -> Bq
#pragma unroll
  for (int rd = 0; rd < 8; rd++)
    gll16(qg + (size_t)(rd * 16 + srow) * 3072, (char*)Bq + rd * 4096 + tid * 16);
  __syncthreads();

  const int rx = l31 & 15;
  bf16x8 qf[8];
  {
    const char* qb = (const char*)Bq + (wave * 32 + l31) * 256;
#pragma unroll
    for (int ks = 0; ks < 8; ks++)
      qf[ks] = *(const bf16x8*)(qb + (((ks * 2 + l5) ^ rx) << 4));
  }
  // stage K0 -> Ak
#pragma unroll
  for (int rd = 0; rd < 8; rd++)
    gll16(kg0 + (size_t)(rd * 16 + srow) * 3072, (char*)Ak + rd * 4096 + tid * 16);
  __syncthreads();   // qf reads done (barrier drains lgkm), K0 resident

  floatx16 oacc[4] = {};
  float lsum = 0.f;

  for (int kt = 0; kt < 16; kt++) {
    if (kt) __syncthreads();   // PV reads of Bq done; K_kt staging drained

    // issue V_kt -> Bq; overlaps QK + softmax below
#pragma unroll
    for (int rd = 0; rd < 8; rd++)
      gll16(vg0 + (size_t)kt * 128 + (size_t)(rd * 16 + srow) * 2048,
            (char*)Bq + rd * 4096 + tid * 16);

    // S^T = K Q^T : D[s][q], col q = l31, row s = 32nt + 8g + 4l5 + r3
    floatx16 sacc[4] = {};
#pragma unroll
    for (int ks = 0; ks < 8; ks++) {
      const int off = ((ks * 2 + l5) ^ rx) << 4;
      const char* kb = (const char*)Ak + l31 * 256 + off;
#pragma unroll
      for (int nt = 0; nt < 4; nt++) {
        const bf16x8 ak = *(const bf16x8*)(kb + nt * 8192);
        sacc[nt] = __builtin_amdgcn_mfma_f32_32x32x16_bf16(ak, qf[ks], sacc[nt], 0, 0, 0);
      }
    }

    // p = exp(s*scale); in-lane sum (q = l31); pack to bf16 pairs.
    // block idx = 4nt + g holds s = 32nt + 8g + 4*l5 + r3 (r3 = 0..3)
    unsigned int pk0[16], pk1[16];
#pragma unroll
    for (int idx = 0; idx < 16; idx++) {
      const int nt = idx >> 2, g4 = (idx & 3) * 4;
      const float p0 = __expf(sacc[nt][g4 + 0] * scale);
      const float p1 = __expf(sacc[nt][g4 + 1] * scale);
      const float p2 = __expf(sacc[nt][g4 + 2] * scale);
      const float p3 = __expf(sacc[nt][g4 + 3] * scale);
      lsum += (p0 + p1) + (p2 + p3);
      pk0[idx] = (unsigned int)(unsigned short)bfbits(p0) |
                 ((unsigned int)(unsigned short)bfbits(p1) << 16);
      pk1[idx] = (unsigned int)(unsigned short)bfbits(p2) |
                 ((unsigned int)(unsigned short)bfbits(p3) << 16);
    }
    // P^T B-frags: frag ks needs block (2ks+l5): j<4 from l5h=0 lane,
    // j>=4 from l5h=1 lane -> one cross-half exchange per ks.
    bf16x8 pf[8];
#pragma unroll
    for (int ks = 0; ks < 8; ks++) {
      const unsigned int own0 = l5 ? pk0[ks * 2 + 1] : pk0[ks * 2];
      const unsigned int own1 = l5 ? pk1[ks * 2 + 1] : pk1[ks * 2];
      const unsigned int snd0 = l5 ? pk0[ks * 2] : pk0[ks * 2 + 1];
      const unsigned int snd1 = l5 ? pk1[ks * 2] : pk1[ks * 2 + 1];
      const unsigned int rc0 = (unsigned int)__shfl_xor((int)snd0, 32);
      const unsigned int rc1 = (unsigned int)__shfl_xor((int)snd1, 32);
      union { int4 i; bf16x8 v; } u;
      u.i.x = l5 ? (int)rc0 : (int)own0;
      u.i.y = l5 ? (int)rc1 : (int)own1;
      u.i.z = l5 ? (int)own0 : (int)rc0;
      u.i.w = l5 ? (int)own1 : (int)rc1;
      pf[ks] = u.v;
    }

    __syncthreads();   // V_kt resident; QK reads of Ak done
    if (kt < 15) {     // issue K_{kt+1} -> Ak; overlaps PV below
#pragma unroll
      for (int rd = 0; rd < 8; rd++)
        gll16(kg0 + (size_t)((kt + 1) * 128 + rd * 16 + srow) * 3072,
              (char*)Ak + rd * 4096 + tid * 16);
    }

    // O^T[hd][q] += V^T P^T : A = Vt rows hd (Bq), B = pf
#pragma unroll
    for (int ks = 0; ks < 8; ks++) {
      const int off = ((ks * 2 + l5) ^ rx) << 4;
      const char* vb = (const char*)Bq + l31 * 256 + off;
#pragma unroll
      for (int nt = 0; nt < 4; nt++) {
        const bf16x8 av = *(const bf16x8*)(vb + nt * 8192);
        oacc[nt] = __builtin_amdgcn_mfma_f32_32x32x16_bf16(av, pf[ks], oacc[nt], 0, 0, 0);
      }
    }
  }

  lsum += __shfl_xor(lsum, 32);
  const float linv = 1.f / lsum;

  // D layout: col q = l31, row hd = 32nt + 8g + 4l5 + r3 -> short4 stores
  const size_t row = tokbase + (size_t)qt * 128 + wave * 32 + l31;
  __hip_bfloat16* vrow = vals + row * 1024 + h * 128 + 4 * l5;
#pragma unroll
  for (int nt = 0; nt < 4; nt++)
#pragma unroll
    for (int g = 0; g < 4; g++) {
      short4 sv;
      sv.x = bfbits(oacc[nt][g * 4 + 0] * linv);
      sv.y = bfbits(oacc[nt][g * 4 + 1] * linv);
      sv.z = bfbits(oacc[nt][g * 4 + 2] * linv);
      sv.w = bfbits(oacc[nt][g * 4 + 3] * linv);
      *(short4*)(vrow + nt * 32 + g * 8) = sv;
    }
}

// --------------------------- aux kernels -----------------------------------
__global__ __launch_bounds__(256) void cvt_bf16_k(const float* __restrict__ in,
                                                  __hip_bfloat16* __restrict__ out) {
  const size_t i = (size_t)blockIdx.x * 256 + threadIdx.x;
  const float4 v = ((const float4*)in)[i];
  short4 sv;
  sv.x = bfbits(v.x); sv.y = bfbits(v.y); sv.z = bfbits(v.z); sv.w = bfbits(v.w);
  ((short4*)out)[i] = sv;
}

__global__ __launch_bounds__(256) void wtrans_k(const float* __restrict__ W,
                                                __hip_bfloat16* __restrict__ WT,
                                                int K, int N) {
  __shared__ float t[32][33];
  const int tx = threadIdx.x & 31, ty = threadIdx.x >> 5;
  const int n0 = blockIdx.x * 32, k0 = blockIdx.y * 32;
#pragma unroll
  for (int i = 0; i < 4; i++)
    t[ty + i * 8][tx] = W[(size_t)(k0 + ty + i * 8) * N + n0 + tx];
  __syncthreads();
#pragma unroll
  for (int i = 0; i < 4; i++)
    WT[(size_t)(n0 + ty + i * 8) * K + k0 + tx] = __float2bfloat16(t[tx][ty + i * 8]);
}

__global__ __launch_bounds__(256) void vtrans_k(const __hip_bfloat16* __restrict__ qkv,
                                                __hip_bfloat16* __restrict__ Vt) {
  __shared__ __hip_bfloat16 t[32][33];
  const int tx = threadIdx.x & 31, ty = threadIdx.x >> 5;
  const int s0 = blockIdx.x * 32, d0 = blockIdx.y * 32, bh = blockIdx.z;
  const int b = bh >> 3, h = bh & 7;
#pragma unroll
  for (int i = 0; i < 4; i++)
    t[ty + i * 8][tx] = qkv[((size_t)b * 2048 + s0 + ty + i * 8) * 3072 + h * 384 + 256 + d0 + tx];
  __syncthreads();
#pragma unroll
  for (int i = 0; i < 4; i++)
    Vt[((size_t)bh * 128 + d0 + ty + i * 8) * 2048 + s0 + tx] = t[tx][ty + i * 8];
}

// Fused split-K reduce + residual + LayerNorm over 1024.
template<bool RES_BF16, bool FINAL>
__global__ __launch_bounds__(256) void ln_red_k(
    const float* __restrict__ p0, const float* __restrict__ p1,
    const float* __restrict__ resf, const __hip_bfloat16* __restrict__ resb,
    __hip_bfloat16* __restrict__ ob, float* __restrict__ of) {
  const int row = blockIdx.x, tid = threadIdx.x;
  const size_t base = (size_t)row * 1024;
  const float4 a = ((const float4*)(p0 + base))[tid];
  const float4 bb = ((const float4*)(p1 + base))[tid];
  float4 v;
  if (RES_BF16) {
    const short4 rb = ((const short4*)(resb + base))[tid];
    v.x = a.x + bb.x + __bfloat162float(*(const __hip_bfloat16*)&rb.x);
    v.y = a.y + bb.y + __bfloat162float(*(const __hip_bfloat16*)&rb.y);
    v.z = a.z + bb.z + __bfloat162float(*(const __hip_bfloat16*)&rb.z);
    v.w = a.w + bb.w + __bfloat162float(*(const __hip_bfloat16*)&rb.w);
  } else {
    const float4 rf = ((const float4*)(resf + base))[tid];
    v.x = a.x + bb.x + rf.x; v.y = a.y + bb.y + rf.y;
    v.z = a.z + bb.z + rf.z; v.w = a.w + bb.w + rf.w;
  }
  float s = v.x + v.y + v.z + v.w;
  float q = v.x * v.x + v.y * v.y + v.z * v.z + v.w * v.w;
#pragma unroll
  for (int off = 32; off; off >>= 1) { s += __shfl_xor(s, off); q += __shfl_xor(q, off); }
  __shared__ float ss[4], sq[4];
  const int wave = tid >> 6;
  if ((tid & 63) == 0) { ss[wave] = s; sq[wave] = q; }
  __syncthreads();
  s = ss[0] + ss[1] + ss[2] + ss[3];
  q = sq[0] + sq[1] + sq[2] + sq[3];
  const float mean = s * (1.f / 1024.f);
  const float var = q * (1.f / 1024.f) - mean * mean;
  const float rstd = rsqrtf(var + 1e-5f);
  float4 o;
  o.x = (v.x - mean) * rstd; o.y = (v.y - mean) * rstd;
  o.z = (v.z - mean) * rstd; o.w = (v.w - mean) * rstd;
  if (FINAL) {
    ((float4*)(of + base))[tid] = o;
  } else {
    short4 sv;
    sv.x = bfbits(o.x); sv.y = bfbits(o.y); sv.z = bfbits(o.z); sv.w = bfbits(o.w);
    ((short4*)(ob + base))[tid] = sv;
  }
}

// ---------------------------------------------------------------------------
extern "C" void kernel_launch(void* const* d_in, const int* in_sizes, int n_in,
                              void* d_out, int out_size, void* d_ws, size_t ws_size,
                              hipStream_t stream) {
  const float* x    = (const float*)d_in[0];
  const float* qkvw = (const float*)d_in[1];
  const float* ow   = (const float*)d_in[2];
  const float* f1   = (const float*)d_in[3];
  const float* f2   = (const float*)d_in[4];
  float* out = (float*)d_out;

  char* ws = (char*)d_ws;
  const size_t MB = 1024 * 1024;
  __hip_bfloat16* xb   = (__hip_bfloat16*)(ws);            // 0..16  (dead after qkv gemm)
  __hip_bfloat16* vals = xb;                                // 0..16  (attn out)
  float*          P1f  = (float*)(ws);                      // 0..32  (ff2 partial z=1)
  __hip_bfloat16* qkvT = (__hip_bfloat16*)(ws + 16 * MB);  // 16..22
  __hip_bfloat16* oT   = (__hip_bfloat16*)(ws + 22 * MB);  // 22..24
  __hip_bfloat16* f1T  = (__hip_bfloat16*)(ws + 24 * MB);  // 24..32
  __hip_bfloat16* f2T  = (__hip_bfloat16*)(ws + 32 * MB);  // 32..40
  __hip_bfloat16* qkvb = (__hip_bfloat16*)(ws + 40 * MB);  // 40..88 (dead after attn)
  __hip_bfloat16* Vt   = (__hip_bfloat16*)(ws + 88 * MB);  // 88..104 (dead after attn)
  float*          P0o  = (float*)(ws + 40 * MB);            // 40..72
  float*          P1o  = (float*)(ws + 72 * MB);            // 72..104
  __hip_bfloat16* hmid = (__hip_bfloat16*)(ws + 40 * MB);   // 40..104 (ff1 out)
  float*          P0f  = (float*)(ws + 104 * MB);           // 104..136
  __hip_bfloat16* x1b  = (__hip_bfloat16*)(ws + 136 * MB);  // 136..152
  (void)in_sizes; (void)n_in; (void)out_size; (void)ws_size;

  cvt_bf16_k<<<8192, 256, 0, stream>>>(x, xb);
  wtrans_k<<<dim3(96, 32), 256, 0, stream>>>(qkvw, qkvT, 1024, 3072);
  wtrans_k<<<dim3(32, 32), 256, 0, stream>>>(ow, oT, 1024, 1024);
  wtrans_k<<<dim3(128, 32), 256, 0, stream>>>(f1, f1T, 1024, 4096);
  wtrans_k<<<dim3(32, 128), 256, 0, stream>>>(f2, f2T, 4096, 1024);
  gemm_bt<0, 1><<<dim3(64, 24, 1), 256, 0, stream>>>(xb, qkvT, nullptr, nullptr,
                                                     qkvb, 8192, 3072, 1024);
  vtrans_k<<<dim3(64, 4, 32), 256, 0, stream>>>(qkvb, Vt);
  attn_kernel<<<dim3(16, 32), 256, 0, stream>>>(qkvb, Vt, vals);
  gemm_bt<4, 2><<<dim3(64, 8, 2), 256, 0, stream>>>(vals, oT, P0o, P1o,
                                                    nullptr, 8192, 1024, 1024);
  ln_red_k<false, false><<<8192, 256, 0, stream>>>(P0o, P1o, x, nullptr, x1b, nullptr);
  gemm_bt<2, 1><<<dim3(64, 32, 1), 256, 0, stream>>>(x1b, f1T, nullptr, nullptr,
                                                     hmid, 8192, 4096, 1024);
  gemm_bt<4, 2><<<dim3(64, 8, 2), 256, 0, stream>>>(hmid, f2T, P0f, P1f,
                                                    nullptr, 8192, 1024, 4096);
  ln_red_k<true, true><<<8192, 256, 0, stream>>>(P0f, P1f, nullptr, x1b, nullptr, out);
}

// Round 6
// 456.167 us; speedup vs baseline: 1.0973x; 1.0973x over previous
//
#include <hip/hip_runtime.h>
#include <hip/hip_bf16.h>

// B=4, S=2048, D=1024, H=8, HD=128, FF=4096
// bf16 MFMA (f32 acc); fp32 softmax/LayerNorm.
// R1: XOR-swizzled LDS -> bank conflicts killed.
// R3: attn on 32x32x16 MFMA, Q in regs, single-pass softmax (max=0).
// R4: GEMM BK=64, split-K=2 on N=1024 GEMMs, LN-fused reduction.
// R5: attn pipelined K-loop, P^T built in registers via shfl_xor(32).
// R6: attn grid bh-major (all qt of a bh on one XCD -> K/V L2-resident),
//     v_perm round-half-up bf16 pack (3 insts/pair vs ~9 RNE),
//     prep kernels merged (1 launch instead of 5).

typedef float floatx4 __attribute__((ext_vector_type(4)));
typedef float floatx16 __attribute__((ext_vector_type(16)));
typedef short bf16x8 __attribute__((ext_vector_type(8)));

#define DEVI __device__ __forceinline__

typedef const __attribute__((address_space(1))) unsigned int* gas1_t;
typedef __attribute__((address_space(3))) unsigned int* las3_t;

DEVI void gll16(const void* g, void* l) {
  __builtin_amdgcn_global_load_lds((gas1_t)g, (las3_t)l, 16, 0, 0);
}

DEVI short bfbits(float f) {
  __hip_bfloat16 h = __float2bfloat16(f);
  return *reinterpret_cast<short*>(&h);
}

// pack two f32 -> two bf16 (round-half-up): 2 v_add + 1 v_perm
DEVI unsigned int packbf(float lo, float hi) {
  return __builtin_amdgcn_perm(__float_as_uint(hi) + 0x8000u,
                               __float_as_uint(lo) + 0x8000u,
                               0x07060302u);
}

// ---------------------------------------------------------------------------
// C[M,N] = A[M,K](bf16 rm) * BT[N,K](bf16 rm). BK=64, 128x128 tile.
// EPI 0: C bf16 | 2: C bf16 = relu(acc) | 4: f32 partial (split-K)
// ---------------------------------------------------------------------------
template<int EPI, int SPLITK>
__global__ __launch_bounds__(256, 4) void gemm_bt(
    const __hip_bfloat16* __restrict__ A,
    const __hip_bfloat16* __restrict__ BT,
    float* __restrict__ Cf, float* __restrict__ Cf2,
    __hip_bfloat16* __restrict__ Cb,
    int M, int N, int K)
{
  __shared__ __hip_bfloat16 As[128 * 64];
  __shared__ __hip_bfloat16 Bs[128 * 64];
  const int tid = threadIdx.x;
  const int wave = tid >> 6, lane = tid & 63;
  const int lane15 = lane & 15, quad = lane >> 4;
  const int row0 = blockIdx.x * 128, col0 = blockIdx.y * 128;
  const int wr = (wave >> 1) * 64, wc = (wave & 1) * 64;
  const int Kh = K / SPLITK;
  const size_t kofs = (SPLITK > 1) ? (size_t)blockIdx.z * Kh : 0;

  floatx4 acc[4][4] = {};

  const int srow = tid >> 3;
  const int sblk = (tid & 7) ^ (srow & 7);
  const __hip_bfloat16* Ag = A + (size_t)(row0 + srow) * K + kofs + sblk * 8;
  const __hip_bfloat16* Bg = BT + (size_t)(col0 + srow) * K + kofs + sblk * 8;
  char* Asl = (char*)As + tid * 16;
  char* Bsl = (char*)Bs + tid * 16;
  const size_t rstep = (size_t)32 * K;

  const int x7 = lane15 & 7;
  for (int k0 = 0; k0 < Kh; k0 += 64) {
    __syncthreads();
#pragma unroll
    for (int p = 0; p < 4; p++) {
      gll16(Ag + k0 + p * rstep, Asl + p * 4096);
      gll16(Bg + k0 + p * rstep, Bsl + p * 4096);
    }
    __syncthreads();
#pragma unroll
    for (int kc = 0; kc < 2; kc++) {
      bf16x8 af[4], bb[4];
#pragma unroll
      for (int t = 0; t < 4; t++) {
        const int r = wr + t * 16 + lane15;
        af[t] = *(const bf16x8*)((const char*)As + r * 128 + (((kc * 4 + quad) ^ x7) << 4));
      }
#pragma unroll
      for (int t = 0; t < 4; t++) {
        const int r = wc + t * 16 + lane15;
        bb[t] = *(const bf16x8*)((const char*)Bs + r * 128 + (((kc * 4 + quad) ^ x7) << 4));
      }
#pragma unroll
      for (int i = 0; i < 4; i++)
#pragma unroll
        for (int j = 0; j < 4; j++)
          acc[i][j] = __builtin_amdgcn_mfma_f32_16x16x32_bf16(af[i], bb[j], acc[i][j], 0, 0, 0);
    }
  }

  float* Cp = (SPLITK > 1 && blockIdx.z) ? Cf2 : Cf;
#pragma unroll
  for (int i = 0; i < 4; i++) {
    const int mb = row0 + wr + i * 16 + quad * 4;
#pragma unroll
    for (int j = 0; j < 4; j++) {
      const int n = col0 + wc + j * 16 + lane15;
#pragma unroll
      for (int r = 0; r < 4; r++) {
        const size_t idx = (size_t)(mb + r) * N + n;
        const float v = acc[i][j][r];
        if (EPI == 0) {
          Cb[idx] = __float2bfloat16(v);
        } else if (EPI == 2) {
          Cb[idx] = __float2bfloat16(v > 0.f ? v : 0.f);
        } else {
          Cp[idx] = v;
        }
      }
    }
  }
}

// ---------------------------------------------------------------------------
// Flash attention, pipelined. Grid (32 b*h, 16 q-tiles) -> linear id =
// bh + 32*qt -> XCD = bh&7: all qt-blocks of a bh share one XCD's L2
// (4 bh x 1MB K/V per XCD). 4 waves; wave owns 32 q (q = wave*32 + l31).
// S^T = K*Q^T so each lane holds the full P row for its q; P^T B-frags
// built via shfl_xor(32). Two LDS buffers, 2 barriers/kt.
// ---------------------------------------------------------------------------
__global__ __launch_bounds__(256, 2) void attn_kernel(
    const __hip_bfloat16* __restrict__ qkv,
    const __hip_bfloat16* __restrict__ Vt,
    __hip_bfloat16* __restrict__ vals)
{
  __shared__ __hip_bfloat16 Ak[128 * 128];   // K tiles
  __shared__ __hip_bfloat16 Bq[128 * 128];   // Q, then V tiles

  const int tid = threadIdx.x;
  const int wave = tid >> 6, lane = tid & 63;
  const int l31 = lane & 31, l5 = lane >> 5;
  const int bh = blockIdx.x, qt = blockIdx.y;   // bh-major for XCD locality
  const int b = bh >> 3, h = bh & 7;
  const size_t tokbase = (size_t)b * 2048;
  const float scale = 0.08838834764831845f;  // 1/sqrt(128)

  const int sw8 = ((tid & 15) ^ (tid >> 4)) * 8;
  const int srow = tid >> 4;
  const __hip_bfloat16* qg  = qkv + (tokbase + qt * 128) * 3072 + h * 384 + sw8;
  const __hip_bfloat16* kg0 = qkv + tokbase * 3072 + h * 384 + 128 + sw8;
  const __hip_bfloat16* vg0 = Vt + (size_t)bh * 128 * 2048 + sw8;

  // stage Q -> Bq
#pragma unroll
  for (int rd = 0; rd < 8; rd++)
    gll16(qg + (size_t)(rd * 16 + srow) * 3072, (char*)Bq + rd * 4096 + tid * 16);
  __syncthreads();

  const int rx = l31 & 15;
  bf16x8 qf[8];
  {
    const char* qb = (const char*)Bq + (wave * 32 + l31) * 256;
#pragma unroll
    for (int ks = 0; ks < 8; ks++)
      qf[ks] = *(const bf16x8*)(qb + (((ks * 2 + l5) ^ rx) << 4));
  }
  // stage K0 -> Ak
#pragma unroll
  for (int rd = 0; rd < 8; rd++)
    gll16(kg0 + (size_t)(rd * 16 + srow) * 3072, (char*)Ak + rd * 4096 + tid * 16);
  __syncthreads();   // qf reads done, K0 resident

  floatx16 oacc[4] = {};
  float lsum = 0.f;

  for (int kt = 0; kt < 16; kt++) {
    if (kt) __syncthreads();   // PV reads of Bq done; K_kt staging drained

    // issue V_kt -> Bq; overlaps QK + softmax below
#pragma unroll
    for (int rd = 0; rd < 8; rd++)
      gll16(vg0 + (size_t)kt * 128 + (size_t)(rd * 16 + srow) * 2048,
            (char*)Bq + rd * 4096 + tid * 16);

    // S^T = K Q^T : D[s][q], col q = l31, row s = 32nt + 8g + 4l5 + r3
    floatx16 sacc[4] = {};
#pragma unroll
    for (int ks = 0; ks < 8; ks++) {
      const int off = ((ks * 2 + l5) ^ rx) << 4;
      const char* kb = (const char*)Ak + l31 * 256 + off;
#pragma unroll
      for (int nt = 0; nt < 4; nt++) {
        const bf16x8 ak = *(const bf16x8*)(kb + nt * 8192);
        sacc[nt] = __builtin_amdgcn_mfma_f32_32x32x16_bf16(ak, qf[ks], sacc[nt], 0, 0, 0);
      }
    }

    // p = exp(s*scale); in-lane sum (q = l31); cheap pack to bf16 pairs.
    unsigned int pk0[16], pk1[16];
#pragma unroll
    for (int idx = 0; idx < 16; idx++) {
      const int nt = idx >> 2, g4 = (idx & 3) * 4;
      const float p0 = __expf(sacc[nt][g4 + 0] * scale);
      const float p1 = __expf(sacc[nt][g4 + 1] * scale);
      const float p2 = __expf(sacc[nt][g4 + 2] * scale);
      const float p3 = __expf(sacc[nt][g4 + 3] * scale);
      lsum += (p0 + p1) + (p2 + p3);
      pk0[idx] = packbf(p0, p1);
      pk1[idx] = packbf(p2, p3);
    }
    // P^T B-frags: one cross-half exchange per ks
    bf16x8 pf[8];
#pragma unroll
    for (int ks = 0; ks < 8; ks++) {
      const unsigned int own0 = l5 ? pk0[ks * 2 + 1] : pk0[ks * 2];
      const unsigned int own1 = l5 ? pk1[ks * 2 + 1] : pk1[ks * 2];
      const unsigned int snd0 = l5 ? pk0[ks * 2] : pk0[ks * 2 + 1];
      const unsigned int snd1 = l5 ? pk1[ks * 2] : pk1[ks * 2 + 1];
      const unsigned int rc0 = (unsigned int)__shfl_xor((int)snd0, 32);
      const unsigned int rc1 = (unsigned int)__shfl_xor((int)snd1, 32);
      union { int4 i; bf16x8 v; } u;
      u.i.x = l5 ? (int)rc0 : (int)own0;
      u.i.y = l5 ? (int)rc1 : (int)own1;
      u.i.z = l5 ? (int)own0 : (int)rc0;
      u.i.w = l5 ? (int)own1 : (int)rc1;
      pf[ks] = u.v;
    }

    __syncthreads();   // V_kt resident; QK reads of Ak done
    if (kt < 15) {     // issue K_{kt+1} -> Ak; overlaps PV below
#pragma unroll
      for (int rd = 0; rd < 8; rd++)
        gll16(kg0 + (size_t)((kt + 1) * 128 + rd * 16 + srow) * 3072,
              (char*)Ak + rd * 4096 + tid * 16);
    }

    // O^T[hd][q] += V^T P^T : A = Vt rows hd (Bq), B = pf
#pragma unroll
    for (int ks = 0; ks < 8; ks++) {
      const int off = ((ks * 2 + l5) ^ rx) << 4;
      const char* vb = (const char*)Bq + l31 * 256 + off;
#pragma unroll
      for (int nt = 0; nt < 4; nt++) {
        const bf16x8 av = *(const bf16x8*)(vb + nt * 8192);
        oacc[nt] = __builtin_amdgcn_mfma_f32_32x32x16_bf16(av, pf[ks], oacc[nt], 0, 0, 0);
      }
    }
  }

  lsum += __shfl_xor(lsum, 32);
  const float linv = 1.f / lsum;

  // D layout: col q = l31, row hd = 32nt + 8g + 4l5 + r3 -> 8B stores
  const size_t row = tokbase + (size_t)qt * 128 + wave * 32 + l31;
  __hip_bfloat16* vrow = vals + row * 1024 + h * 128 + 4 * l5;
#pragma unroll
  for (int nt = 0; nt < 4; nt++)
#pragma unroll
    for (int g = 0; g < 4; g++) {
      uint2 pk;
      pk.x = packbf(oacc[nt][g * 4 + 0] * linv, oacc[nt][g * 4 + 1] * linv);
      pk.y = packbf(oacc[nt][g * 4 + 2] * linv, oacc[nt][g * 4 + 3] * linv);
      *(uint2*)(vrow + nt * 32 + g * 8) = pk;
    }
}

// --------------------------- aux kernels -----------------------------------
// Merged prep: blocks [0,8192) cast x to bf16; remaining blocks transpose+cast
// the four weight matrices (W[K,N] f32 -> WT[N,K] bf16).
__global__ __launch_bounds__(256) void prep_k(
    const float* __restrict__ x, __hip_bfloat16* __restrict__ xb,
    const float* __restrict__ qkvw, __hip_bfloat16* __restrict__ qkvT,
    const float* __restrict__ ow, __hip_bfloat16* __restrict__ oT,
    const float* __restrict__ f1, __hip_bfloat16* __restrict__ f1T,
    const float* __restrict__ f2, __hip_bfloat16* __restrict__ f2T)
{
  const int bid = blockIdx.x;
  if (bid < 8192) {
    const size_t i = (size_t)bid * 256 + threadIdx.x;
    const float4 v = ((const float4*)x)[i];
    short4 sv;
    sv.x = bfbits(v.x); sv.y = bfbits(v.y); sv.z = bfbits(v.z); sv.w = bfbits(v.w);
    ((short4*)xb)[i] = sv;
    return;
  }
  int t = bid - 8192;
  const float* W; __hip_bfloat16* WT; int K, N, nbx;
  if (t < 3072) { W = qkvw; WT = qkvT; K = 1024; N = 3072; nbx = 96; }
  else if (t < 3072 + 1024) { t -= 3072; W = ow; WT = oT; K = 1024; N = 1024; nbx = 32; }
  else if (t < 3072 + 1024 + 4096) { t -= 3072 + 1024; W = f1; WT = f1T; K = 1024; N = 4096; nbx = 128; }
  else { t -= 3072 + 1024 + 4096; W = f2; WT = f2T; K = 4096; N = 1024; nbx = 32; }
  __shared__ float tl[32][33];
  const int tx = threadIdx.x & 31, ty = threadIdx.x >> 5;
  const int n0 = (t % nbx) * 32, k0 = (t / nbx) * 32;
#pragma unroll
  for (int i = 0; i < 4; i++)
    tl[ty + i * 8][tx] = W[(size_t)(k0 + ty + i * 8) * N + n0 + tx];
  __syncthreads();
#pragma unroll
  for (int i = 0; i < 4; i++)
    WT[(size_t)(n0 + ty + i * 8) * K + k0 + tx] = __float2bfloat16(tl[tx][ty + i * 8]);
}

__global__ __launch_bounds__(256) void vtrans_k(const __hip_bfloat16* __restrict__ qkv,
                                                __hip_bfloat16* __restrict__ Vt) {
  __shared__ __hip_bfloat16 t[32][33];
  const int tx = threadIdx.x & 31, ty = threadIdx.x >> 5;
  const int s0 = blockIdx.x * 32, d0 = blockIdx.y * 32, bh = blockIdx.z;
  const int b = bh >> 3, h = bh & 7;
#pragma unroll
  for (int i = 0; i < 4; i++)
    t[ty + i * 8][tx] = qkv[((size_t)b * 2048 + s0 + ty + i * 8) * 3072 + h * 384 + 256 + d0 + tx];
  __syncthreads();
#pragma unroll
  for (int i = 0; i < 4; i++)
    Vt[((size_t)bh * 128 + d0 + ty + i * 8) * 2048 + s0 + tx] = t[tx][ty + i * 8];
}

// Fused split-K reduce + residual + LayerNorm over 1024.
template<bool RES_BF16, bool FINAL>
__global__ __launch_bounds__(256) void ln_red_k(
    const float* __restrict__ p0, const float* __restrict__ p1,
    const float* __restrict__ resf, const __hip_bfloat16* __restrict__ resb,
    __hip_bfloat16* __restrict__ ob, float* __restrict__ of) {
  const int row = blockIdx.x, tid = threadIdx.x;
  const size_t base = (size_t)row * 1024;
  const float4 a = ((const float4*)(p0 + base))[tid];
  const float4 bb = ((const float4*)(p1 + base))[tid];
  float4 v;
  if (RES_BF16) {
    const short4 rb = ((const short4*)(resb + base))[tid];
    v.x = a.x + bb.x + __bfloat162float(*(const __hip_bfloat16*)&rb.x);
    v.y = a.y + bb.y + __bfloat162float(*(const __hip_bfloat16*)&rb.y);
    v.z = a.z + bb.z + __bfloat162float(*(const __hip_bfloat16*)&rb.z);
    v.w = a.w + bb.w + __bfloat162float(*(const __hip_bfloat16*)&rb.w);
  } else {
    const float4 rf = ((const float4*)(resf + base))[tid];
    v.x = a.x + bb.x + rf.x; v.y = a.y + bb.y + rf.y;
    v.z = a.z + bb.z + rf.z; v.w = a.w + bb.w + rf.w;
  }
  float s = v.x + v.y + v.z + v.w;
  float q = v.x * v.x + v.y * v.y + v.z * v.z + v.w * v.w;
#pragma unroll
  for (int off = 32; off; off >>= 1) { s += __shfl_xor(s, off); q += __shfl_xor(q, off); }
  __shared__ float ss[4], sq[4];
  const int wave = tid >> 6;
  if ((tid & 63) == 0) { ss[wave] = s; sq[wave] = q; }
  __syncthreads();
  s = ss[0] + ss[1] + ss[2] + ss[3];
  q = sq[0] + sq[1] + sq[2] + sq[3];
  const float mean = s * (1.f / 1024.f);
  const float var = q * (1.f / 1024.f) - mean * mean;
  const float rstd = rsqrtf(var + 1e-5f);
  float4 o;
  o.x = (v.x - mean) * rstd; o.y = (v.y - mean) * rstd;
  o.z = (v.z - mean) * rstd; o.w = (v.w - mean) * rstd;
  if (FINAL) {
    ((float4*)(of + base))[tid] = o;
  } else {
    short4 sv;
    sv.x = bfbits(o.x); sv.y = bfbits(o.y); sv.z = bfbits(o.z); sv.w = bfbits(o.w);
    ((short4*)(ob + base))[tid] = sv;
  }
}

// ---------------------------------------------------------------------------
extern "C" void kernel_launch(void* const* d_in, const int* in_sizes, int n_in,
                              void* d_out, int out_size, void* d_ws, size_t ws_size,
                              hipStream_t stream) {
  const float* x    = (const float*)d_in[0];
  const float* qkvw = (const float*)d_in[1];
  const float* ow   = (const float*)d_in[2];
  const float* f1   = (const float*)d_in[3];
  const float* f2   = (const float*)d_in[4];
  float* out = (float*)d_out;

  char* ws = (char*)d_ws;
  const size_t MB = 1024 * 1024;
  __hip_bfloat16* xb   = (__hip_bfloat16*)(ws);            // 0..16  (dead after qkv gemm)
  __hip_bfloat16* vals = xb;                                // 0..16  (attn out)
  float*          P1f  = (float*)(ws);                      // 0..32  (ff2 partial z=1)
  __hip_bfloat16* qkvT = (__hip_bfloat16*)(ws + 16 * MB);  // 16..22
  __hip_bfloat16* oT   = (__hip_bfloat16*)(ws + 22 * MB);  // 22..24
  __hip_bfloat16* f1T  = (__hip_bfloat16*)(ws + 24 * MB);  // 24..32
  __hip_bfloat16* f2T  = (__hip_bfloat16*)(ws + 32 * MB);  // 32..40
  __hip_bfloat16* qkvb = (__hip_bfloat16*)(ws + 40 * MB);  // 40..88 (dead after attn)
  __hip_bfloat16* Vt   = (__hip_bfloat16*)(ws + 88 * MB);  // 88..104 (dead after attn)
  float*          P0o  = (float*)(ws + 40 * MB);            // 40..72
  float*          P1o  = (float*)(ws + 72 * MB);            // 72..104
  __hip_bfloat16* hmid = (__hip_bfloat16*)(ws + 40 * MB);   // 40..104 (ff1 out)
  float*          P0f  = (float*)(ws + 104 * MB);           // 104..136
  __hip_bfloat16* x1b  = (__hip_bfloat16*)(ws + 136 * MB);  // 136..152
  (void)in_sizes; (void)n_in; (void)out_size; (void)ws_size;

  // merged prep: x cast (8192 blocks) + 4 weight transposes (12288 blocks)
  prep_k<<<20480, 256, 0, stream>>>(x, xb, qkvw, qkvT, ow, oT, f1, f1T, f2, f2T);
  gemm_bt<0, 1><<<dim3(64, 24, 1), 256, 0, stream>>>(xb, qkvT, nullptr, nullptr,
                                                     qkvb, 8192, 3072, 1024);
  vtrans_k<<<dim3(64, 4, 32), 256, 0, stream>>>(qkvb, Vt);
  attn_kernel<<<dim3(32, 16), 256, 0, stream>>>(qkvb, Vt, vals);
  gemm_bt<4, 2><<<dim3(64, 8, 2), 256, 0, stream>>>(vals, oT, P0o, P1o,
                                                    nullptr, 8192, 1024, 1024);
  ln_red_k<false, false><<<8192, 256, 0, stream>>>(P0o, P1o, x, nullptr, x1b, nullptr);
  gemm_bt<2, 1><<<dim3(64, 32, 1), 256, 0, stream>>>(x1b, f1T, nullptr, nullptr,
                                                     hmid, 8192, 4096, 1024);
  gemm_bt<4, 2><<<dim3(64, 8, 2), 256, 0, stream>>>(hmid, f2T, P0f, P1f,
                                                    nullptr, 8192, 1024, 4096);
  ln_red_k<true, true><<<8192, 256, 0, stream>>>(P0f, P1f, nullptr, x1b, nullptr, out);
}

// Round 7
// 441.793 us; speedup vs baseline: 1.1330x; 1.0325x over previous
//
#include <hip/hip_runtime.h>
#include <hip/hip_bf16.h>

// B=4, S=2048, D=1024, H=8, HD=128, FF=4096
// R1: XOR-swizzled LDS. R3: 32x32x16 attn, Q in regs, max=0 softmax.
// R4: GEMM BK=64, split-K=2, LN-fused reduce. R5: pipelined attn K-loop,
// P^T in regs. R6: bh-major grid (XCD L2 locality), cheap bf16 pack.
// R7: K-tile rows staged with bit2<->bit3 permutation so P^T B-frags are
//     built fully in-lane (no ds_bpermute shuffles, no selects);
//     Q pre-scaled by scale*log2e in qkv epilogue -> attn exp is raw exp2;
//     split-K partials + residuals in bf16 (LN reads halved).

typedef float floatx4 __attribute__((ext_vector_type(4)));
typedef float floatx16 __attribute__((ext_vector_type(16)));
typedef short bf16x8 __attribute__((ext_vector_type(8)));

#define DEVI __device__ __forceinline__

typedef const __attribute__((address_space(1))) unsigned int* gas1_t;
typedef __attribute__((address_space(3))) unsigned int* las3_t;

DEVI void gll16(const void* g, void* l) {
  __builtin_amdgcn_global_load_lds((gas1_t)g, (las3_t)l, 16, 0, 0);
}

DEVI short bfbits(float f) {
  __hip_bfloat16 h = __float2bfloat16(f);
  return *reinterpret_cast<short*>(&h);
}

// pack two f32 -> two bf16 (round-half-up): 2 v_add + 1 v_perm
DEVI unsigned int packbf(float lo, float hi) {
  return __builtin_amdgcn_perm(__float_as_uint(hi) + 0x8000u,
                               __float_as_uint(lo) + 0x8000u,
                               0x07060302u);
}

// ---------------------------------------------------------------------------
// C[M,N] = A[M,K](bf16 rm) * BT[N,K](bf16 rm). BK=64, 128x128 tile.
// EPI 0: C bf16, Q-columns pre-scaled by scale*log2e (qkv only)
// EPI 2: C bf16 = relu(acc) | EPI 4: bf16 partial (split-K; z -> Cb/Cb2)
// ---------------------------------------------------------------------------
template<int EPI, int SPLITK>
__global__ __launch_bounds__(256, 4) void gemm_bt(
    const __hip_bfloat16* __restrict__ A,
    const __hip_bfloat16* __restrict__ BT,
    __hip_bfloat16* __restrict__ Cb, __hip_bfloat16* __restrict__ Cb2,
    int M, int N, int K)
{
  __shared__ __hip_bfloat16 As[128 * 64];
  __shared__ __hip_bfloat16 Bs[128 * 64];
  const int tid = threadIdx.x;
  const int wave = tid >> 6, lane = tid & 63;
  const int lane15 = lane & 15, quad = lane >> 4;
  const int row0 = blockIdx.x * 128, col0 = blockIdx.y * 128;
  const int wr = (wave >> 1) * 64, wc = (wave & 1) * 64;
  const int Kh = K / SPLITK;
  const size_t kofs = (SPLITK > 1) ? (size_t)blockIdx.z * Kh : 0;

  floatx4 acc[4][4] = {};

  const int srow = tid >> 3;
  const int sblk = (tid & 7) ^ (srow & 7);
  const __hip_bfloat16* Ag = A + (size_t)(row0 + srow) * K + kofs + sblk * 8;
  const __hip_bfloat16* Bg = BT + (size_t)(col0 + srow) * K + kofs + sblk * 8;
  char* Asl = (char*)As + tid * 16;
  char* Bsl = (char*)Bs + tid * 16;
  const size_t rstep = (size_t)32 * K;

  const int x7 = lane15 & 7;
  for (int k0 = 0; k0 < Kh; k0 += 64) {
    __syncthreads();
#pragma unroll
    for (int p = 0; p < 4; p++) {
      gll16(Ag + k0 + p * rstep, Asl + p * 4096);
      gll16(Bg + k0 + p * rstep, Bsl + p * 4096);
    }
    __syncthreads();
#pragma unroll
    for (int kc = 0; kc < 2; kc++) {
      bf16x8 af[4], bb[4];
#pragma unroll
      for (int t = 0; t < 4; t++) {
        const int r = wr + t * 16 + lane15;
        af[t] = *(const bf16x8*)((const char*)As + r * 128 + (((kc * 4 + quad) ^ x7) << 4));
      }
#pragma unroll
      for (int t = 0; t < 4; t++) {
        const int r = wc + t * 16 + lane15;
        bb[t] = *(const bf16x8*)((const char*)Bs + r * 128 + (((kc * 4 + quad) ^ x7) << 4));
      }
#pragma unroll
      for (int i = 0; i < 4; i++)
#pragma unroll
        for (int j = 0; j < 4; j++)
          acc[i][j] = __builtin_amdgcn_mfma_f32_16x16x32_bf16(af[i], bb[j], acc[i][j], 0, 0, 0);
    }
  }

  __hip_bfloat16* Cp = (SPLITK > 1 && blockIdx.z) ? Cb2 : Cb;
#pragma unroll
  for (int i = 0; i < 4; i++) {
    const int mb = row0 + wr + i * 16 + quad * 4;
#pragma unroll
    for (int j = 0; j < 4; j++) {
      const int n = col0 + wc + j * 16 + lane15;
      // qkv only: scale Q-columns by 1/sqrt(128)*log2(e) for exp2 softmax
      const float fac = (EPI == 0 && (((n >> 7) % 3) == 0)) ? 0.12751729f : 1.f;
#pragma unroll
      for (int r = 0; r < 4; r++) {
        const size_t idx = (size_t)(mb + r) * N + n;
        const float v = acc[i][j][r];
        if (EPI == 0) {
          Cb[idx] = __float2bfloat16(v * fac);
        } else if (EPI == 2) {
          Cb[idx] = __float2bfloat16(v > 0.f ? v : 0.f);
        } else {
          Cp[idx] = __float2bfloat16(v);
        }
      }
    }
  }
}

// ---------------------------------------------------------------------------
// Flash attention, pipelined. Grid (32 bh, 16 qt), bh-major -> XCD locality.
// 4 waves; wave owns 32 q (q = wave*32 + l31). S^T = K*Q^T with K-tile rows
// staged bit2<->bit3-permuted: the D-slot for key s' lands on the SAME lane
// as its B-operand slot -> pf built in-lane (no shuffles):
//   pf[c].j = exp2(sacc[c>>1][8*(c&1)+j]),  s' = 16c + 8*l5 + j.
// Q pre-scaled in qkv GEMM -> p = exp2(s) directly. 2 barriers/kt.
// ---------------------------------------------------------------------------
__global__ __launch_bounds__(256, 2) void attn_kernel(
    const __hip_bfloat16* __restrict__ qkv,
    const __hip_bfloat16* __restrict__ Vt,
    __hip_bfloat16* __restrict__ vals)
{
  __shared__ __hip_bfloat16 Ak[128 * 128];   // K tiles (row-permuted)
  __shared__ __hip_bfloat16 Bq[128 * 128];   // Q, then V tiles

  const int tid = threadIdx.x;
  const int wave = tid >> 6, lane = tid & 63;
  const int l31 = lane & 31, l5 = lane >> 5;
  const int bh = blockIdx.x, qt = blockIdx.y;
  const int b = bh >> 3, h = bh & 7;
  const size_t tokbase = (size_t)b * 2048;

  const int sw8 = ((tid & 15) ^ (tid >> 4)) * 8;
  const int srow = tid >> 4;
  // bit2<->bit3 swap of the tile-local staging row (K only)
  const int srowp = (srow & 3) | ((srow << 1) & 8) | ((srow >> 1) & 4);
  const __hip_bfloat16* qg  = qkv + (tokbase + qt * 128) * 3072 + h * 384 + sw8;
  const __hip_bfloat16* kg0 = qkv + tokbase * 3072 + h * 384 + 128 + sw8;
  const __hip_bfloat16* vg0 = Vt + (size_t)bh * 128 * 2048 + sw8;

  // stage Q -> Bq
#pragma unroll
  for (int rd = 0; rd < 8; rd++)
    gll16(qg + (size_t)(rd * 16 + srow) * 3072, (char*)Bq + rd * 4096 + tid * 16);
  __syncthreads();

  const int rx = l31 & 15;
  bf16x8 qf[8];
  {
    const char* qb = (const char*)Bq + (wave * 32 + l31) * 256;
#pragma unroll
    for (int ks = 0; ks < 8; ks++)
      qf[ks] = *(const bf16x8*)(qb + (((ks * 2 + l5) ^ rx) << 4));
  }
  // stage K0 -> Ak (permuted rows)
#pragma unroll
  for (int rd = 0; rd < 8; rd++)
    gll16(kg0 + (size_t)(rd * 16 + srowp) * 3072, (char*)Ak + rd * 4096 + tid * 16);
  __syncthreads();   // qf reads done, K0 resident

  floatx16 oacc[4] = {};
  float lsum = 0.f;

  for (int kt = 0; kt < 16; kt++) {
    if (kt) __syncthreads();   // PV reads of Bq done; K_kt staging drained

    // issue V_kt -> Bq; overlaps QK + softmax below
#pragma unroll
    for (int rd = 0; rd < 8; rd++)
      gll16(vg0 + (size_t)kt * 128 + (size_t)(rd * 16 + srow) * 2048,
            (char*)Bq + rd * 4096 + tid * 16);

    // S^T = K Q^T : D[s][q], col q = l31
    floatx16 sacc[4] = {};
#pragma unroll
    for (int ks = 0; ks < 8; ks++) {
      const int off = ((ks * 2 + l5) ^ rx) << 4;
      const char* kb = (const char*)Ak + l31 * 256 + off;
#pragma unroll
      for (int nt = 0; nt < 4; nt++) {
        const bf16x8 ak = *(const bf16x8*)(kb + nt * 8192);
        sacc[nt] = __builtin_amdgcn_mfma_f32_32x32x16_bf16(ak, qf[ks], sacc[nt], 0, 0, 0);
      }
    }

    // p = exp2(s); in-lane sum; in-lane B-frag construction (key perm)
    bf16x8 pf[8];
#pragma unroll
    for (int c = 0; c < 8; c++) {
      const int nt = c >> 1, bi = (c & 1) * 8;
      const float p0 = exp2f(sacc[nt][bi + 0]);
      const float p1 = exp2f(sacc[nt][bi + 1]);
      const float p2 = exp2f(sacc[nt][bi + 2]);
      const float p3 = exp2f(sacc[nt][bi + 3]);
      const float p4 = exp2f(sacc[nt][bi + 4]);
      const float p5 = exp2f(sacc[nt][bi + 5]);
      const float p6 = exp2f(sacc[nt][bi + 6]);
      const float p7 = exp2f(sacc[nt][bi + 7]);
      lsum += ((p0 + p1) + (p2 + p3)) + ((p4 + p5) + (p6 + p7));
      union { uint4 u; bf16x8 v; } w;
      w.u.x = packbf(p0, p1); w.u.y = packbf(p2, p3);
      w.u.z = packbf(p4, p5); w.u.w = packbf(p6, p7);
      pf[c] = w.v;
    }

    __syncthreads();   // V_kt resident; QK reads of Ak done
    if (kt < 15) {     // issue K_{kt+1} -> Ak; overlaps PV below
#pragma unroll
      for (int rd = 0; rd < 8; rd++)
        gll16(kg0 + (size_t)((kt + 1) * 128 + rd * 16 + srowp) * 3072,
              (char*)Ak + rd * 4096 + tid * 16);
    }

    // O^T[hd][q] += V^T P^T : A = Vt rows hd (Bq), B = pf
#pragma unroll
    for (int ks = 0; ks < 8; ks++) {
      const int off = ((ks * 2 + l5) ^ rx) << 4;
      const char* vb = (const char*)Bq + l31 * 256 + off;
#pragma unroll
      for (int nt = 0; nt < 4; nt++) {
        const bf16x8 av = *(const bf16x8*)(vb + nt * 8192);
        oacc[nt] = __builtin_amdgcn_mfma_f32_32x32x16_bf16(av, pf[ks], oacc[nt], 0, 0, 0);
      }
    }
  }

  lsum += __shfl_xor(lsum, 32);
  const float linv = 1.f / lsum;

  // D layout: col q = l31, row hd = 32nt + 8g + 4l5 + r3 -> 8B stores
  const size_t row = tokbase + (size_t)qt * 128 + wave * 32 + l31;
  __hip_bfloat16* vrow = vals + row * 1024 + h * 128 + 4 * l5;
#pragma unroll
  for (int nt = 0; nt < 4; nt++)
#pragma unroll
    for (int g = 0; g < 4; g++) {
      uint2 pk;
      pk.x = packbf(oacc[nt][g * 4 + 0] * linv, oacc[nt][g * 4 + 1] * linv);
      pk.y = packbf(oacc[nt][g * 4 + 2] * linv, oacc[nt][g * 4 + 3] * linv);
      *(uint2*)(vrow + nt * 32 + g * 8) = pk;
    }
}

// --------------------------- aux kernels -----------------------------------
// Merged prep: blocks [0,8192) cast x to bf16; rest transpose+cast weights.
__global__ __launch_bounds__(256) void prep_k(
    const float* __restrict__ x, __hip_bfloat16* __restrict__ xb,
    const float* __restrict__ qkvw, __hip_bfloat16* __restrict__ qkvT,
    const float* __restrict__ ow, __hip_bfloat16* __restrict__ oT,
    const float* __restrict__ f1, __hip_bfloat16* __restrict__ f1T,
    const float* __restrict__ f2, __hip_bfloat16* __restrict__ f2T)
{
  const int bid = blockIdx.x;
  if (bid < 8192) {
    const size_t i = (size_t)bid * 256 + threadIdx.x;
    const float4 v = ((const float4*)x)[i];
    short4 sv;
    sv.x = bfbits(v.x); sv.y = bfbits(v.y); sv.z = bfbits(v.z); sv.w = bfbits(v.w);
    ((short4*)xb)[i] = sv;
    return;
  }
  int t = bid - 8192;
  const float* W; __hip_bfloat16* WT; int K, N, nbx;
  if (t < 3072) { W = qkvw; WT = qkvT; K = 1024; N = 3072; nbx = 96; }
  else if (t < 3072 + 1024) { t -= 3072; W = ow; WT = oT; K = 1024; N = 1024; nbx = 32; }
  else if (t < 3072 + 1024 + 4096) { t -= 3072 + 1024; W = f1; WT = f1T; K = 1024; N = 4096; nbx = 128; }
  else { t -= 3072 + 1024 + 4096; W = f2; WT = f2T; K = 4096; N = 1024; nbx = 32; }
  __shared__ float tl[32][33];
  const int tx = threadIdx.x & 31, ty = threadIdx.x >> 5;
  const int n0 = (t % nbx) * 32, k0 = (t / nbx) * 32;
#pragma unroll
  for (int i = 0; i < 4; i++)
    tl[ty + i * 8][tx] = W[(size_t)(k0 + ty + i * 8) * N + n0 + tx];
  __syncthreads();
#pragma unroll
  for (int i = 0; i < 4; i++)
    WT[(size_t)(n0 + ty + i * 8) * K + k0 + tx] = __float2bfloat16(tl[tx][ty + i * 8]);
}

__global__ __launch_bounds__(256) void vtrans_k(const __hip_bfloat16* __restrict__ qkv,
                                                __hip_bfloat16* __restrict__ Vt) {
  __shared__ __hip_bfloat16 t[32][33];
  const int tx = threadIdx.x & 31, ty = threadIdx.x >> 5;
  const int s0 = blockIdx.x * 32, d0 = blockIdx.y * 32, bh = blockIdx.z;
  const int b = bh >> 3, h = bh & 7;
#pragma unroll
  for (int i = 0; i < 4; i++)
    t[ty + i * 8][tx] = qkv[((size_t)b * 2048 + s0 + ty + i * 8) * 3072 + h * 384 + 256 + d0 + tx];
  __syncthreads();
#pragma unroll
  for (int i = 0; i < 4; i++)
    Vt[((size_t)bh * 128 + d0 + ty + i * 8) * 2048 + s0 + tx] = t[tx][ty + i * 8];
}

// Fused split-K reduce (bf16 partials) + bf16 residual + LayerNorm over 1024.
template<bool FINAL>
__global__ __launch_bounds__(256) void ln_red_k(
    const __hip_bfloat16* __restrict__ p0, const __hip_bfloat16* __restrict__ p1,
    const __hip_bfloat16* __restrict__ res,
    __hip_bfloat16* __restrict__ ob, float* __restrict__ of) {
  const int row = blockIdx.x, tid = threadIdx.x;
  const size_t base = (size_t)row * 1024;
  const short4 a4 = ((const short4*)(p0 + base))[tid];
  const short4 b4 = ((const short4*)(p1 + base))[tid];
  const short4 r4 = ((const short4*)(res + base))[tid];
#define BF(x) __bfloat162float(*(const __hip_bfloat16*)&(x))
  float4 v;
  v.x = BF(a4.x) + BF(b4.x) + BF(r4.x);
  v.y = BF(a4.y) + BF(b4.y) + BF(r4.y);
  v.z = BF(a4.z) + BF(b4.z) + BF(r4.z);
  v.w = BF(a4.w) + BF(b4.w) + BF(r4.w);
#undef BF
  float s = v.x + v.y + v.z + v.w;
  float q = v.x * v.x + v.y * v.y + v.z * v.z + v.w * v.w;
#pragma unroll
  for (int off = 32; off; off >>= 1) { s += __shfl_xor(s, off); q += __shfl_xor(q, off); }
  __shared__ float ss[4], sq[4];
  const int wave = tid >> 6;
  if ((tid & 63) == 0) { ss[wave] = s; sq[wave] = q; }
  __syncthreads();
  s = ss[0] + ss[1] + ss[2] + ss[3];
  q = sq[0] + sq[1] + sq[2] + sq[3];
  const float mean = s * (1.f / 1024.f);
  const float var = q * (1.f / 1024.f) - mean * mean;
  const float rstd = rsqrtf(var + 1e-5f);
  float4 o;
  o.x = (v.x - mean) * rstd; o.y = (v.y - mean) * rstd;
  o.z = (v.z - mean) * rstd; o.w = (v.w - mean) * rstd;
  if (FINAL) {
    ((float4*)(of + base))[tid] = o;
  } else {
    short4 sv;
    sv.x = bfbits(o.x); sv.y = bfbits(o.y); sv.z = bfbits(o.z); sv.w = bfbits(o.w);
    ((short4*)(ob + base))[tid] = sv;
  }
}

// ---------------------------------------------------------------------------
extern "C" void kernel_launch(void* const* d_in, const int* in_sizes, int n_in,
                              void* d_out, int out_size, void* d_ws, size_t ws_size,
                              hipStream_t stream) {
  const float* x    = (const float*)d_in[0];
  const float* qkvw = (const float*)d_in[1];
  const float* ow   = (const float*)d_in[2];
  const float* f1   = (const float*)d_in[3];
  const float* f2   = (const float*)d_in[4];
  float* out = (float*)d_out;

  char* ws = (char*)d_ws;
  const size_t MB = 1024 * 1024;
  // ws layout (152 MB):
  __hip_bfloat16* xb   = (__hip_bfloat16*)(ws);             // 0..16   (alive to LN1)
  __hip_bfloat16* vals = (__hip_bfloat16*)(ws + 16 * MB);   // 16..32  (attn out, to o_proj)
  __hip_bfloat16* P1f  = (__hip_bfloat16*)(ws + 16 * MB);   // 16..32  (ff2 z=1, after vals dead)
  __hip_bfloat16* qkvT = (__hip_bfloat16*)(ws + 32 * MB);   // 32..38
  __hip_bfloat16* oT   = (__hip_bfloat16*)(ws + 38 * MB);   // 38..40
  __hip_bfloat16* f1T  = (__hip_bfloat16*)(ws + 40 * MB);   // 40..48
  __hip_bfloat16* f2T  = (__hip_bfloat16*)(ws + 48 * MB);   // 48..56
  __hip_bfloat16* qkvb = (__hip_bfloat16*)(ws + 56 * MB);   // 56..104 (to attn)
  __hip_bfloat16* P0o  = (__hip_bfloat16*)(ws + 56 * MB);   // 56..72  (after qkvb dead)
  __hip_bfloat16* P1o  = (__hip_bfloat16*)(ws + 72 * MB);   // 72..88
  __hip_bfloat16* hmid = (__hip_bfloat16*)(ws + 56 * MB);   // 56..120 (after LN1)
  __hip_bfloat16* Vt   = (__hip_bfloat16*)(ws + 104 * MB);  // 104..120 (to attn)
  __hip_bfloat16* x1b  = (__hip_bfloat16*)(ws + 120 * MB);  // 120..136 (to final LN)
  __hip_bfloat16* P0f  = (__hip_bfloat16*)(ws + 136 * MB);  // 136..152
  (void)in_sizes; (void)n_in; (void)out_size; (void)ws_size;

  // merged prep: x cast (8192 blocks) + 4 weight transposes (12288 blocks)
  prep_k<<<20480, 256, 0, stream>>>(x, xb, qkvw, qkvT, ow, oT, f1, f1T, f2, f2T);
  // qkv = x @ qkv_proj (bf16; Q-cols pre-scaled for exp2 softmax)
  gemm_bt<0, 1><<<dim3(64, 24, 1), 256, 0, stream>>>(xb, qkvT, qkvb, nullptr,
                                                     8192, 3072, 1024);
  vtrans_k<<<dim3(64, 4, 32), 256, 0, stream>>>(qkvb, Vt);
  attn_kernel<<<dim3(32, 16), 256, 0, stream>>>(qkvb, Vt, vals);
  // o_proj partials (split-K=2, bf16)
  gemm_bt<4, 2><<<dim3(64, 8, 2), 256, 0, stream>>>(vals, oT, P0o, P1o,
                                                    8192, 1024, 1024);
  // x1 = LN(P0o + P1o + x) (bf16)
  ln_red_k<false><<<8192, 256, 0, stream>>>(P0o, P1o, xb, x1b, nullptr);
  // h = relu(x1 @ ff1) (bf16)
  gemm_bt<2, 1><<<dim3(64, 32, 1), 256, 0, stream>>>(x1b, f1T, hmid, nullptr,
                                                     8192, 4096, 1024);
  // ff2 partials (split-K=2, bf16)
  gemm_bt<4, 2><<<dim3(64, 8, 2), 256, 0, stream>>>(hmid, f2T, P0f, P1f,
                                                    8192, 1024, 4096);
  // out = LN(P0f + P1f + x1) (f32)
  ln_red_k<true><<<8192, 256, 0, stream>>>(P0f, P1f, x1b, nullptr, out);
}